// Round 1
// baseline (6587.965 us; speedup 1.0000x reference)
//
#include <hip/hip_runtime.h>

__device__ __forceinline__ float frelu(float v){ return fmaxf(v, 0.f); }

// ---------- k1: h1 = relu(x @ W1.T + b1), x[N][5], W1[64][5] ----------
__global__ __launch_bounds__(256) void k_lin5(const float* __restrict__ x,
    const float* __restrict__ W1, const float* __restrict__ b1,
    float* __restrict__ out, int n)
{
  int t = blockIdx.x*256 + threadIdx.x;
  int node = t >> 6, c = t & 63;
  if (node >= n) return;
  float acc = b1[c];
  const float* xr = x + (size_t)node*5;
  const float* wr = W1 + c*5;
  #pragma unroll
  for (int k=0;k<5;k++) acc = fmaf(xr[k], wr[k], acc);
  out[(size_t)node*64 + c] = frelu(acc);
}

// ---------- generic row-GEMM: Out[n][c] = EPI( sum_k PRE(A[n][k]) * W[c][k] ) ----------
// PRE: 0 = identity, 1 = relu(a + bpre[k])
// EPI: 0 = none, 1 = +bpost, 2 = relu(+bpost), 3 = relu(+bpost) + A[n][c] (needs K==COLS)
template<int K, int COLS, int COLS_REAL, int PRE, int EPI>
__global__ __launch_bounds__(512) void k_gemm(const float* __restrict__ A,
    const float* __restrict__ W, const float* __restrict__ bpre,
    const float* __restrict__ bpost, float* __restrict__ Out, int n)
{
  __shared__ float Wl[COLS][K+1];   // pitch K+1: bank = (c+k)%32, conflict-free reads
  __shared__ float At[64][K+4];     // pitch K+4: float4-aligned
  const int tid = threadIdx.x;
  // stage W: global float4 (k-fast, coalesced) -> LDS scalar writes
  for (int idx = tid; idx < COLS*(K/4); idx += 512) {
    int k0 = (idx % (K/4))*4;
    int c  = idx / (K/4);
    float4 w;
    if (COLS_REAL == COLS || c < COLS_REAL) w = *(const float4*)(W + (size_t)c*K + k0);
    else w = make_float4(0.f,0.f,0.f,0.f);
    Wl[c][k0+0]=w.x; Wl[c][k0+1]=w.y; Wl[c][k0+2]=w.z; Wl[c][k0+3]=w.w;
  }
  // stage A tile (64 rows)
  const int nb = blockIdx.x*64;
  for (int idx = tid; idx < 64*(K/4); idx += 512) {
    int k0 = (idx % (K/4))*4;
    int r  = idx / (K/4);
    float4 a = make_float4(0.f,0.f,0.f,0.f);
    if (nb + r < n) a = *(const float4*)(A + (size_t)(nb+r)*K + k0);
    if (PRE) {
      a.x = frelu(a.x + bpre[k0+0]);
      a.y = frelu(a.y + bpre[k0+1]);
      a.z = frelu(a.z + bpre[k0+2]);
      a.w = frelu(a.w + bpre[k0+3]);
    }
    *(float4*)&At[r][k0] = a;
  }
  __syncthreads();
  constexpr int CS  = COLS/4;   // col groups; thread's cols are cg + j*CS
  constexpr int NNG = 512/CS;   // node groups
  constexpr int RPT = 64/NNG;   // rows per thread
  const int cg = tid % CS;
  const int ng = tid / CS;
  float acc[RPT][4];
  #pragma unroll
  for (int i=0;i<RPT;i++){ acc[i][0]=0.f; acc[i][1]=0.f; acc[i][2]=0.f; acc[i][3]=0.f; }
  for (int k=0; k<K; k+=4) {
    float4 av[RPT];
    #pragma unroll
    for (int i=0;i<RPT;i++) av[i] = *(const float4*)&At[ng + i*NNG][k];
    #pragma unroll
    for (int j=0;j<4;j++) {
      const int c = cg + j*CS;
      const float w0 = Wl[c][k+0], w1 = Wl[c][k+1], w2 = Wl[c][k+2], w3 = Wl[c][k+3];
      #pragma unroll
      for (int i=0;i<RPT;i++) {
        acc[i][j] = fmaf(av[i].x, w0, acc[i][j]);
        acc[i][j] = fmaf(av[i].y, w1, acc[i][j]);
        acc[i][j] = fmaf(av[i].z, w2, acc[i][j]);
        acc[i][j] = fmaf(av[i].w, w3, acc[i][j]);
      }
    }
  }
  #pragma unroll
  for (int i=0;i<RPT;i++) {
    const int r = ng + i*NNG;
    const int node = nb + r;
    if (node >= n) continue;
    #pragma unroll
    for (int j=0;j<4;j++) {
      const int c = cg + j*CS;
      if (COLS_REAL != COLS && c >= COLS_REAL) continue;
      float v = acc[i][j];
      if (EPI >= 1) v += bpost[c];
      if (EPI >= 2) v = frelu(v);
      if (EPI == 3) v += At[r][c];
      Out[(size_t)node*COLS_REAL + c] = v;
    }
  }
}

// ---------- degree / dinv ----------
__global__ __launch_bounds__(256) void k_fill1(float* __restrict__ d, int n){
  int i = blockIdx.x*256 + threadIdx.x;
  if (i < n) d[i] = 1.f;   // self-loop contributes 1
}
__global__ __launch_bounds__(256) void k_deg(const int* __restrict__ dst, float* __restrict__ deg, int E){
  int e = blockIdx.x*256 + threadIdx.x;
  if (e < E) atomicAdd(&deg[dst[e]], 1.f);
}
__global__ __launch_bounds__(256) void k_rsqrt(float* __restrict__ d, int n){
  int i = blockIdx.x*256 + threadIdx.x;
  if (i < n) d[i] = rsqrtf(d[i]);
}

// ---------- aggregation ----------
// init: out[i] = t[i] * dinv[i]^2  (self-loop message)
__global__ __launch_bounds__(256) void k_selfinit(const float* __restrict__ t,
    const float* __restrict__ dinv, float* __restrict__ out, int n){
  int i = blockIdx.x*256 + threadIdx.x;     // n*32 float4 chunks
  int node = i >> 5, c4 = (i & 31) << 2;
  if (node >= n) return;
  float s = dinv[node]; s *= s;
  float4 v = *(const float4*)(t + (size_t)node*128 + c4);
  v.x*=s; v.y*=s; v.z*=s; v.w*=s;
  *(float4*)(out + (size_t)node*128 + c4) = v;
}
// one wave per edge: out[dst] += t[src] * dinv[src]*dinv[dst]
__global__ __launch_bounds__(256) void k_scatter(const int* __restrict__ src,
    const int* __restrict__ dst, const float* __restrict__ dinv,
    const float* __restrict__ t, float* __restrict__ out, int E)
{
  int gw = (blockIdx.x*256 + threadIdx.x) >> 6;
  int lane = threadIdx.x & 63;
  if (gw >= E) return;
  int s = src[gw], d = dst[gw];
  float nrm = dinv[s]*dinv[d];
  float2 v = *(const float2*)(t + (size_t)s*128 + (lane<<1));
  float* o = out + (size_t)d*128 + (lane<<1);
  atomicAdd(o+0, v.x*nrm);
  atomicAdd(o+1, v.y*nrm);
}

extern "C" void kernel_launch(void* const* d_in, const int* in_sizes, int n_in,
                              void* d_out, int out_size, void* d_ws, size_t ws_size,
                              hipStream_t stream)
{
  const float* x   = (const float*)d_in[0];
  const int*   ei  = (const int*)d_in[1];
  const float *W1=(const float*)d_in[2],  *b1=(const float*)d_in[3];
  const float *W2=(const float*)d_in[4],  *b2=(const float*)d_in[5];
  const float *W3=(const float*)d_in[6],  *b3=(const float*)d_in[7];
  const float *W4=(const float*)d_in[8],  *b4=(const float*)d_in[9];
  const float *Wc1=(const float*)d_in[10],*bc1=(const float*)d_in[11];
  const float *Wc2=(const float*)d_in[12],*bc2=(const float*)d_in[13];
  const float *W5=(const float*)d_in[14], *b5=(const float*)d_in[15];
  float* out = (float*)d_out;

  const int n = in_sizes[0] / 5;
  const int E = in_sizes[1] / 2;
  const int* esrc = ei;
  const int* edst = ei + E;

  float* hA   = (float*)d_ws;               // n*128 f32
  float* hB   = hA + (size_t)n*128;         // n*128 f32
  float* dinv = hB + (size_t)n*128;         // n f32

  const int GB = (n + 63)/64;
  dim3 B256(256), B512(512);

  // --- MLP head ---
  k_lin5<<<dim3((n*64 + 255)/256), B256, 0, stream>>>(x, W1, b1, hA, n);
  k_gemm<64,128,128,0,2><<<dim3(GB), B512, 0, stream>>>(hA, W2, nullptr, b2, hB, n);   // h2
  k_gemm<128,128,128,0,3><<<dim3(GB), B512, 0, stream>>>(hB, W3, nullptr, b3, hB, n);  // h3 (in-place)
  k_gemm<128,128,128,0,3><<<dim3(GB), B512, 0, stream>>>(hB, W4, nullptr, b4, hB, n);  // h4 (in-place)

  // --- degrees ---
  k_fill1<<<dim3((n + 255)/256), B256, 0, stream>>>(dinv, n);
  k_deg<<<dim3((E + 255)/256), B256, 0, stream>>>(edst, dinv, E);
  k_rsqrt<<<dim3((n + 255)/256), B256, 0, stream>>>(dinv, n);

  // --- GCN conv 1: t1 = h4 @ Wc1.T ; agg1 = scatter(t1) ---
  k_gemm<128,128,128,0,0><<<dim3(GB), B512, 0, stream>>>(hB, Wc1, nullptr, nullptr, hA, n); // t1 -> hA
  k_selfinit<<<dim3((n*32 + 255)/256), B256, 0, stream>>>(hA, dinv, hB, n);                 // agg1 -> hB
  k_scatter<<<dim3((E + 3)/4), B256, 0, stream>>>(esrc, edst, dinv, hA, hB, E);

  // --- GCN conv 2: t2 = relu(agg1+bc1) @ Wc2.T ; agg2 = scatter(t2) ---
  k_gemm<128,128,128,1,0><<<dim3(GB), B512, 0, stream>>>(hB, Wc2, bc1, nullptr, hB, n);     // t2 (in-place)
  k_selfinit<<<dim3((n*32 + 255)/256), B256, 0, stream>>>(hB, dinv, hA, n);                 // agg2 -> hA
  k_scatter<<<dim3((E + 3)/4), B256, 0, stream>>>(esrc, edst, dinv, hB, hA, E);

  // --- final: out = relu(agg2+bc2) @ W5.T + b5 ---
  k_gemm<128,64,60,1,1><<<dim3(GB), B512, 0, stream>>>(hA, W5, bc2, b5, out, n);
}

// Round 2
// 2067.284 us; speedup vs baseline: 3.1868x; 3.1868x over previous
//
#include <hip/hip_runtime.h>

__device__ __forceinline__ float frelu(float v){ return fmaxf(v, 0.f); }

// ---------- k1: h1 = relu(x @ W1.T + b1), x[N][5], W1[64][5] ----------
__global__ __launch_bounds__(256) void k_lin5(const float* __restrict__ x,
    const float* __restrict__ W1, const float* __restrict__ b1,
    float* __restrict__ out, int n)
{
  int t = blockIdx.x*256 + threadIdx.x;
  int node = t >> 6, c = t & 63;
  if (node >= n) return;
  float acc = b1[c];
  const float* xr = x + (size_t)node*5;
  const float* wr = W1 + c*5;
  #pragma unroll
  for (int k=0;k<5;k++) acc = fmaf(xr[k], wr[k], acc);
  out[(size_t)node*64 + c] = frelu(acc);
}

// ---------- generic row-GEMM: Out[n][c] = EPI( sum_k PRE(A[n][k]) * W[c][k] ) ----------
// PRE: 0 = identity, 1 = relu(a + bpre[k])
// EPI: 0 = none, 1 = +bpost, 2 = relu(+bpost), 3 = relu(+bpost)+A[n][c], 4 = *dscale[node]
template<int K, int COLS, int COLS_REAL, int PRE, int EPI>
__global__ __launch_bounds__(512) void k_gemm(const float* __restrict__ A,
    const float* __restrict__ W, const float* __restrict__ bpre,
    const float* __restrict__ bpost, const float* __restrict__ dscale,
    float* __restrict__ Out, int n)
{
  __shared__ float Wl[COLS][K+1];   // pitch K+1: conflict-free scalar reads
  __shared__ float At[64][K+4];     // pitch K+4: float4-aligned
  const int tid = threadIdx.x;
  for (int idx = tid; idx < COLS*(K/4); idx += 512) {
    int k0 = (idx % (K/4))*4;
    int c  = idx / (K/4);
    float4 w;
    if (COLS_REAL == COLS || c < COLS_REAL) w = *(const float4*)(W + (size_t)c*K + k0);
    else w = make_float4(0.f,0.f,0.f,0.f);
    Wl[c][k0+0]=w.x; Wl[c][k0+1]=w.y; Wl[c][k0+2]=w.z; Wl[c][k0+3]=w.w;
  }
  const int nb = blockIdx.x*64;
  for (int idx = tid; idx < 64*(K/4); idx += 512) {
    int k0 = (idx % (K/4))*4;
    int r  = idx / (K/4);
    float4 a = make_float4(0.f,0.f,0.f,0.f);
    if (nb + r < n) a = *(const float4*)(A + (size_t)(nb+r)*K + k0);
    if (PRE) {
      a.x = frelu(a.x + bpre[k0+0]);
      a.y = frelu(a.y + bpre[k0+1]);
      a.z = frelu(a.z + bpre[k0+2]);
      a.w = frelu(a.w + bpre[k0+3]);
    }
    *(float4*)&At[r][k0] = a;
  }
  __syncthreads();
  constexpr int CS  = COLS/4;
  constexpr int NNG = 512/CS;
  constexpr int RPT = 64/NNG;
  const int cg = tid % CS;
  const int ng = tid / CS;
  float acc[RPT][4];
  #pragma unroll
  for (int i=0;i<RPT;i++){ acc[i][0]=0.f; acc[i][1]=0.f; acc[i][2]=0.f; acc[i][3]=0.f; }
  for (int k=0; k<K; k+=4) {
    float4 av[RPT];
    #pragma unroll
    for (int i=0;i<RPT;i++) av[i] = *(const float4*)&At[ng + i*NNG][k];
    #pragma unroll
    for (int j=0;j<4;j++) {
      const int c = cg + j*CS;
      const float w0 = Wl[c][k+0], w1 = Wl[c][k+1], w2 = Wl[c][k+2], w3 = Wl[c][k+3];
      #pragma unroll
      for (int i=0;i<RPT;i++) {
        acc[i][j] = fmaf(av[i].x, w0, acc[i][j]);
        acc[i][j] = fmaf(av[i].y, w1, acc[i][j]);
        acc[i][j] = fmaf(av[i].z, w2, acc[i][j]);
        acc[i][j] = fmaf(av[i].w, w3, acc[i][j]);
      }
    }
  }
  #pragma unroll
  for (int i=0;i<RPT;i++) {
    const int r = ng + i*NNG;
    const int node = nb + r;
    if (node >= n) continue;
    float ds = 1.f;
    if (EPI == 4) ds = dscale[node];
    #pragma unroll
    for (int j=0;j<4;j++) {
      const int c = cg + j*CS;
      if (COLS_REAL != COLS && c >= COLS_REAL) continue;
      float v = acc[i][j];
      if (EPI == 1 || EPI == 2 || EPI == 3) v += bpost[c];
      if (EPI == 2 || EPI == 3) v = frelu(v);
      if (EPI == 3) v += At[r][c];
      if (EPI == 4) v *= ds;
      Out[(size_t)node*COLS_REAL + c] = v;
    }
  }
}

// ---------- CSR build ----------
__global__ __launch_bounds__(256) void k_zeroi(int* __restrict__ a, int n){
  int i = blockIdx.x*256 + threadIdx.x; if (i<n) a[i]=0;
}
__global__ __launch_bounds__(256) void k_degi(const int* __restrict__ dst, int* __restrict__ cnt, int E){
  int e = blockIdx.x*256 + threadIdx.x; if (e<E) atomicAdd(&cnt[dst[e]], 1);
}
__global__ __launch_bounds__(256) void k_dinv(const int* __restrict__ cnt, float* __restrict__ dinv, int n){
  int i = blockIdx.x*256 + threadIdx.x; if (i<n) dinv[i] = rsqrtf((float)cnt[i] + 1.0f);
}
__global__ __launch_bounds__(256) void k_scan1(int* __restrict__ a, int* __restrict__ bsums, int n){
  __shared__ int sd[256];
  int tid = threadIdx.x;
  int base = blockIdx.x*1024 + tid*4;
  int v0 = (base+0<n)?a[base+0]:0;
  int v1 = (base+1<n)?a[base+1]:0;
  int v2 = (base+2<n)?a[base+2]:0;
  int v3 = (base+3<n)?a[base+3]:0;
  int ts = v0+v1+v2+v3;
  sd[tid]=ts; __syncthreads();
  for (int off=1; off<256; off<<=1){
    int t = (tid>=off)? sd[tid-off] : 0;
    __syncthreads();
    sd[tid]+=t;
    __syncthreads();
  }
  int excl = sd[tid]-ts;
  if (tid==255) bsums[blockIdx.x]=sd[255];
  if (base+0<n) a[base+0]=excl;
  if (base+1<n) a[base+1]=excl+v0;
  if (base+2<n) a[base+2]=excl+v0+v1;
  if (base+3<n) a[base+3]=excl+v0+v1+v2;
}
__global__ void k_scan2(int* __restrict__ bsums, int nb){
  if (threadIdx.x==0 && blockIdx.x==0){
    int run=0;
    for (int i=0;i<nb;i++){ int t=bsums[i]; bsums[i]=run; run+=t; }
  }
}
__global__ __launch_bounds__(256) void k_scan3(int* __restrict__ a, const int* __restrict__ bsums, int n){
  int i = blockIdx.x*256+threadIdx.x;
  if (i<n) a[i]+=bsums[i>>10];
}
__global__ __launch_bounds__(256) void k_reorder(const int* __restrict__ src, const int* __restrict__ dst,
    int* __restrict__ cursor, int* __restrict__ srcs, int E){
  int e = blockIdx.x*256 + threadIdx.x;
  if (e>=E) return;
  int pos = atomicAdd(&cursor[dst[e]], 1);
  srcs[pos] = src[e];
}

// ---------- gather aggregation: out[d] = dinv[d] * (tp[d] + sum_{s in N(d)} tp[s]) ----------
__global__ __launch_bounds__(256) void k_agg(const int* __restrict__ cend,
    const int* __restrict__ srcs, const float* __restrict__ dinv,
    const float* __restrict__ tp, float* __restrict__ out, int n)
{
  int node = blockIdx.x*4 + (threadIdx.x>>6);
  if (node >= n) return;
  const int lane = threadIdx.x & 63;
  const int c = lane<<1;
  int beg = (node==0) ? 0 : cend[node-1];
  int end = cend[node];
  float2 acc = *(const float2*)(tp + (size_t)node*128 + c);
  int e = beg;
  for (; e+4<=end; e+=4){
    int s0=srcs[e], s1=srcs[e+1], s2=srcs[e+2], s3=srcs[e+3];
    float2 v0 = *(const float2*)(tp + (size_t)s0*128 + c);
    float2 v1 = *(const float2*)(tp + (size_t)s1*128 + c);
    float2 v2 = *(const float2*)(tp + (size_t)s2*128 + c);
    float2 v3 = *(const float2*)(tp + (size_t)s3*128 + c);
    acc.x += (v0.x+v1.x) + (v2.x+v3.x);
    acc.y += (v0.y+v1.y) + (v2.y+v3.y);
  }
  for (; e<end; ++e){
    int s = srcs[e];
    float2 v = *(const float2*)(tp + (size_t)s*128 + c);
    acc.x += v.x; acc.y += v.y;
  }
  float di = dinv[node];
  float2 r; r.x = acc.x*di; r.y = acc.y*di;
  *(float2*)(out + (size_t)node*128 + c) = r;
}

// ---------- fallback path kernels (atomic scatter) ----------
__global__ __launch_bounds__(256) void k_fill1(float* __restrict__ d, int n){
  int i = blockIdx.x*256 + threadIdx.x; if (i<n) d[i]=1.f;
}
__global__ __launch_bounds__(256) void k_deg(const int* __restrict__ dst, float* __restrict__ deg, int E){
  int e = blockIdx.x*256 + threadIdx.x; if (e<E) atomicAdd(&deg[dst[e]], 1.f);
}
__global__ __launch_bounds__(256) void k_rsqrt(float* __restrict__ d, int n){
  int i = blockIdx.x*256 + threadIdx.x; if (i<n) d[i]=rsqrtf(d[i]);
}
__global__ __launch_bounds__(256) void k_selfinit(const float* __restrict__ t,
    const float* __restrict__ dinv, float* __restrict__ out, int n){
  int i = blockIdx.x*256 + threadIdx.x;
  int node = i >> 5, c4 = (i & 31) << 2;
  if (node >= n) return;
  float s = dinv[node]; s *= s;
  float4 v = *(const float4*)(t + (size_t)node*128 + c4);
  v.x*=s; v.y*=s; v.z*=s; v.w*=s;
  *(float4*)(out + (size_t)node*128 + c4) = v;
}
__global__ __launch_bounds__(256) void k_scatter(const int* __restrict__ src,
    const int* __restrict__ dst, const float* __restrict__ dinv,
    const float* __restrict__ t, float* __restrict__ out, int E)
{
  int gw = (blockIdx.x*256 + threadIdx.x) >> 6;
  int lane = threadIdx.x & 63;
  if (gw >= E) return;
  int s = src[gw], d = dst[gw];
  float nrm = dinv[s]*dinv[d];
  float2 v = *(const float2*)(t + (size_t)s*128 + (lane<<1));
  float* o = out + (size_t)d*128 + (lane<<1);
  atomicAdd(o+0, v.x*nrm);
  atomicAdd(o+1, v.y*nrm);
}

extern "C" void kernel_launch(void* const* d_in, const int* in_sizes, int n_in,
                              void* d_out, int out_size, void* d_ws, size_t ws_size,
                              hipStream_t stream)
{
  const float* x   = (const float*)d_in[0];
  const int*   ei  = (const int*)d_in[1];
  const float *W1=(const float*)d_in[2],  *b1=(const float*)d_in[3];
  const float *W2=(const float*)d_in[4],  *b2=(const float*)d_in[5];
  const float *W3=(const float*)d_in[6],  *b3=(const float*)d_in[7];
  const float *W4=(const float*)d_in[8],  *b4=(const float*)d_in[9];
  const float *Wc1=(const float*)d_in[10],*bc1=(const float*)d_in[11];
  const float *Wc2=(const float*)d_in[12],*bc2=(const float*)d_in[13];
  const float *W5=(const float*)d_in[14], *b5=(const float*)d_in[15];
  float* out = (float*)d_out;

  const int n = in_sizes[0] / 5;
  const int E = in_sizes[1] / 2;
  const int* esrc = ei;
  const int* edst = ei + E;

  const int GB = (n + 63)/64;
  const int nb = (n + 1023)/1024;
  dim3 B256(256), B512(512);

  // workspace layout
  char* p = (char*)d_ws;
  float* hA   = (float*)p;            p += (size_t)n*128*4;
  float* hB   = (float*)p;            p += (size_t)n*128*4;
  float* dinv = (float*)p;            p += (size_t)n*4;
  int*   cursor = (int*)p;            p += (size_t)n*4;
  int*   bsums  = (int*)p;            p += (size_t)nb*4;
  int*   srcs   = (int*)p;            p += (size_t)E*4;
  const bool csr_ok = ((size_t)(p - (char*)d_ws) <= ws_size);

  // --- MLP head (shared by both paths) ---
  k_lin5<<<dim3((n*64 + 255)/256), B256, 0, stream>>>(x, W1, b1, hA, n);
  k_gemm<64,128,128,0,2><<<dim3(GB), B512, 0, stream>>>(hA, W2, nullptr, b2, nullptr, hB, n);
  k_gemm<128,128,128,0,3><<<dim3(GB), B512, 0, stream>>>(hB, W3, nullptr, b3, nullptr, hB, n);
  k_gemm<128,128,128,0,3><<<dim3(GB), B512, 0, stream>>>(hB, W4, nullptr, b4, nullptr, hB, n);

  if (csr_ok) {
    // --- CSR build ---
    k_zeroi<<<dim3((n+255)/256), B256, 0, stream>>>(cursor, n);
    k_degi<<<dim3((E+255)/256), B256, 0, stream>>>(edst, cursor, E);
    k_dinv<<<dim3((n+255)/256), B256, 0, stream>>>(cursor, dinv, n);
    k_scan1<<<dim3(nb), B256, 0, stream>>>(cursor, bsums, n);
    k_scan2<<<dim3(1), dim3(64), 0, stream>>>(bsums, nb);
    k_scan3<<<dim3((n+255)/256), B256, 0, stream>>>(cursor, bsums, n);
    k_reorder<<<dim3((E+255)/256), B256, 0, stream>>>(esrc, edst, cursor, srcs, E);
    // after k_reorder, cursor[d] = end of segment d

    // --- conv1: tp1 = (h4 @ Wc1.T)*dinv -> hA ; agg1 -> hB ---
    k_gemm<128,128,128,0,4><<<dim3(GB), B512, 0, stream>>>(hB, Wc1, nullptr, nullptr, dinv, hA, n);
    k_agg<<<dim3((n+3)/4), B256, 0, stream>>>(cursor, srcs, dinv, hA, hB, n);

    // --- conv2: tp2 = (relu(agg1+bc1) @ Wc2.T)*dinv -> hA ; agg2 -> hB ---
    k_gemm<128,128,128,1,4><<<dim3(GB), B512, 0, stream>>>(hB, Wc2, bc1, nullptr, dinv, hA, n);
    k_agg<<<dim3((n+3)/4), B256, 0, stream>>>(cursor, srcs, dinv, hA, hB, n);

    // --- final: out = relu(agg2+bc2) @ W5.T + b5 ---
    k_gemm<128,64,60,1,1><<<dim3(GB), B512, 0, stream>>>(hB, W5, bc2, b5, nullptr, out, n);
  } else {
    // --- fallback: atomic scatter path ---
    k_fill1<<<dim3((n + 255)/256), B256, 0, stream>>>(dinv, n);
    k_deg<<<dim3((E + 255)/256), B256, 0, stream>>>(edst, dinv, E);
    k_rsqrt<<<dim3((n + 255)/256), B256, 0, stream>>>(dinv, n);

    k_gemm<128,128,128,0,0><<<dim3(GB), B512, 0, stream>>>(hB, Wc1, nullptr, nullptr, nullptr, hA, n);
    k_selfinit<<<dim3((n*32 + 255)/256), B256, 0, stream>>>(hA, dinv, hB, n);
    k_scatter<<<dim3((E + 3)/4), B256, 0, stream>>>(esrc, edst, dinv, hA, hB, E);

    k_gemm<128,128,128,1,0><<<dim3(GB), B512, 0, stream>>>(hB, Wc2, bc1, nullptr, nullptr, hB, n);
    k_selfinit<<<dim3((n*32 + 255)/256), B256, 0, stream>>>(hB, dinv, hA, n);
    k_scatter<<<dim3((E + 3)/4), B256, 0, stream>>>(esrc, edst, dinv, hB, hA, E);

    k_gemm<128,64,60,1,1><<<dim3(GB), B512, 0, stream>>>(hA, W5, bc2, b5, nullptr, out, n);
  }
}

// Round 3
// 1023.410 us; speedup vs baseline: 6.4373x; 2.0200x over previous
//
#include <hip/hip_runtime.h>

typedef __attribute__((ext_vector_type(8))) short bf16x8;
typedef __attribute__((ext_vector_type(4))) float f32x4;

__device__ __forceinline__ float frelu(float v){ return fmaxf(v, 0.f); }
__device__ __forceinline__ short f2bf(float f){
  unsigned u = __float_as_uint(f);
  unsigned r = (u + 0x7fffu + ((u>>16)&1u)) >> 16;
  return (short)r;
}
__device__ __forceinline__ float bf2f(short h){
  return __uint_as_float(((unsigned)(unsigned short)h) << 16);
}

// ---------- k1: h1 = relu(x @ W1.T + b1), x[N][5], W1[64][5] ----------
__global__ __launch_bounds__(256) void k_lin5(const float* __restrict__ x,
    const float* __restrict__ W1, const float* __restrict__ b1,
    float* __restrict__ out, int n)
{
  int t = blockIdx.x*256 + threadIdx.x;
  int node = t >> 6, c = t & 63;
  if (node >= n) return;
  float acc = b1[c];
  const float* xr = x + (size_t)node*5;
  const float* wr = W1 + c*5;
  #pragma unroll
  for (int k=0;k<5;k++) acc = fmaf(xr[k], wr[k], acc);
  out[(size_t)node*64 + c] = frelu(acc);
}

// ---------- MFMA split-bf16 GEMM: Out = EPI( PRE(A) @ W.T ) ----------
// A [n][K] fp32, W [COLS_REAL][K] fp32. 3-term split: AhWh + AhWl + AlWh.
// PRE: 0 id, 1 relu(a + bpre[k])
// EPI: 1 +bpost, 2 relu(+bpost), 3 relu(+bpost)+A[node][col] (K==BN), 4 *dscale[node]
// Block: 512 thr = 8 waves; tile BM=WRG*64 rows x BN=WCG*64 cols; wave tile 64x64
// (4x4 frags of 16x16, mfma_f32_16x16x32_bf16). K staged in 32-wide chunks.
template<int K, int BN, int COLS_REAL, int PRE, int EPI, int WRG, int WCG>
__global__ __launch_bounds__(512) void k_mgemm(const float* __restrict__ A,
    const float* __restrict__ W, const float* __restrict__ bpre,
    const float* __restrict__ bpost, const float* __restrict__ dscale,
    float* __restrict__ Out, int n)
{
  constexpr int BM = WRG*64;
  __shared__ __align__(16) short sAh[BM*32];
  __shared__ __align__(16) short sAl[BM*32];
  __shared__ __align__(16) short sWh[BN*32];
  __shared__ __align__(16) short sWl[BN*32];

  const int tid = threadIdx.x;
  const int nb0 = blockIdx.x * BM;
  const int l = tid & 63;
  const int w = tid >> 6;
  const int wr = w % WRG;
  const int wc = w / WRG;
  const int lrow = l & 15;
  const int koct = l >> 4;          // 0..3

  f32x4 acc[4][4];
  #pragma unroll
  for (int i=0;i<4;i++)
    #pragma unroll
    for (int j=0;j<4;j++) acc[i][j] = (f32x4){0.f,0.f,0.f,0.f};

  for (int kc = 0; kc < K/32; ++kc) {
    if (kc) __syncthreads();
    // ---- stage A chunk: BM rows x 32 k, split to bf16 hi/lo, swizzled ----
    #pragma unroll
    for (int t = 0; t < BM/128; ++t) {
      int idx = tid + t*512;                 // BM*4 tasks (row, kq)
      int row = idx >> 2, kq = idx & 3;
      int node = nb0 + row;
      float a[8];
      if (node < n) {
        const float* g = A + (size_t)node*K + kc*32 + kq*8;
        float4 v0 = *(const float4*)g;
        float4 v1 = *(const float4*)(g+4);
        a[0]=v0.x; a[1]=v0.y; a[2]=v0.z; a[3]=v0.w;
        a[4]=v1.x; a[5]=v1.y; a[6]=v1.z; a[7]=v1.w;
      } else {
        #pragma unroll
        for (int j=0;j<8;j++) a[j]=0.f;
      }
      if constexpr (PRE == 1) {
        const float* bp = bpre + kc*32 + kq*8;
        float4 b0 = *(const float4*)bp;
        float4 b1 = *(const float4*)(bp+4);
        a[0]=frelu(a[0]+b0.x); a[1]=frelu(a[1]+b0.y);
        a[2]=frelu(a[2]+b0.z); a[3]=frelu(a[3]+b0.w);
        a[4]=frelu(a[4]+b1.x); a[5]=frelu(a[5]+b1.y);
        a[6]=frelu(a[6]+b1.z); a[7]=frelu(a[7]+b1.w);
      }
      union { short s[8]; bf16x8 v; } ph, pl;
      #pragma unroll
      for (int j=0;j<8;j++) {
        short h = f2bf(a[j]);
        ph.s[j] = h;
        pl.s[j] = f2bf(a[j] - bf2f(h));
      }
      int byte = (row<<6) | (kq<<4);
      byte ^= (row&7)<<4;
      *(bf16x8*)((char*)sAh + byte) = ph.v;
      *(bf16x8*)((char*)sAl + byte) = pl.v;
    }
    // ---- stage W chunk: BN cols x 32 k ----
    if (BN*4 >= 512 || tid < BN*4) {
      int idx = tid;                         // BN*4 tasks (c, kq); BN<=128
      int c = idx >> 2, kq = idx & 3;
      float a[8];
      if (COLS_REAL == BN || c < COLS_REAL) {
        const float* g = W + (size_t)c*K + kc*32 + kq*8;
        float4 v0 = *(const float4*)g;
        float4 v1 = *(const float4*)(g+4);
        a[0]=v0.x; a[1]=v0.y; a[2]=v0.z; a[3]=v0.w;
        a[4]=v1.x; a[5]=v1.y; a[6]=v1.z; a[7]=v1.w;
      } else {
        #pragma unroll
        for (int j=0;j<8;j++) a[j]=0.f;
      }
      union { short s[8]; bf16x8 v; } ph, pl;
      #pragma unroll
      for (int j=0;j<8;j++) {
        short h = f2bf(a[j]);
        ph.s[j] = h;
        pl.s[j] = f2bf(a[j] - bf2f(h));
      }
      int byte = (c<<6) | (kq<<4);
      byte ^= (c&7)<<4;
      *(bf16x8*)((char*)sWh + byte) = ph.v;
      *(bf16x8*)((char*)sWl + byte) = pl.v;
    }
    __syncthreads();
    // ---- compute: load frags, 3-term MFMA ----
    bf16x8 fah[4], fal[4], fwh[4], fwl[4];
    #pragma unroll
    for (int rf=0; rf<4; ++rf) {
      int row = wr*64 + rf*16 + lrow;
      int byte = (row<<6) | (koct<<4);
      byte ^= (row&7)<<4;
      fah[rf] = *(const bf16x8*)((const char*)sAh + byte);
      fal[rf] = *(const bf16x8*)((const char*)sAl + byte);
    }
    #pragma unroll
    for (int cf=0; cf<4; ++cf) {
      int c = wc*64 + cf*16 + lrow;
      int byte = (c<<6) | (koct<<4);
      byte ^= (c&7)<<4;
      fwh[cf] = *(const bf16x8*)((const char*)sWh + byte);
      fwl[cf] = *(const bf16x8*)((const char*)sWl + byte);
    }
    #pragma unroll
    for (int rf=0; rf<4; ++rf)
      #pragma unroll
      for (int cf=0; cf<4; ++cf) {
        acc[rf][cf] = __builtin_amdgcn_mfma_f32_16x16x32_bf16(fah[rf], fwh[cf], acc[rf][cf], 0,0,0);
        acc[rf][cf] = __builtin_amdgcn_mfma_f32_16x16x32_bf16(fah[rf], fwl[cf], acc[rf][cf], 0,0,0);
        acc[rf][cf] = __builtin_amdgcn_mfma_f32_16x16x32_bf16(fal[rf], fwh[cf], acc[rf][cf], 0,0,0);
      }
  }
  // ---- epilogue: C[row][col], row=(l>>4)*4+reg, col=l&15 within frag ----
  const int crow = (l >> 4) * 4;
  float bpc[4];
  if constexpr (EPI==1 || EPI==2 || EPI==3) {
    #pragma unroll
    for (int cf=0; cf<4; ++cf) {
      int col = wc*64 + cf*16 + (l & 15);
      bpc[cf] = (COLS_REAL == BN || col < COLS_REAL) ? bpost[col] : 0.f;
    }
  }
  #pragma unroll
  for (int rf=0; rf<4; ++rf) {
    #pragma unroll
    for (int reg=0; reg<4; ++reg) {
      int row = wr*64 + rf*16 + crow + reg;
      int node = nb0 + row;
      if (node >= n) continue;
      float ds = 1.f;
      if constexpr (EPI==4) ds = dscale[node];
      #pragma unroll
      for (int cf=0; cf<4; ++cf) {
        int col = wc*64 + cf*16 + (l & 15);
        if (COLS_REAL != BN && col >= COLS_REAL) continue;
        float v = acc[rf][cf][reg];
        if constexpr (EPI==1) v += bpc[cf];
        if constexpr (EPI==2) v = frelu(v + bpc[cf]);
        if constexpr (EPI==3) v = frelu(v + bpc[cf]) + A[(size_t)node*K + col];
        if constexpr (EPI==4) v *= ds;
        Out[(size_t)node*COLS_REAL + col] = v;
      }
    }
  }
}

// ---------- CSR build ----------
__global__ __launch_bounds__(256) void k_zeroi(int* __restrict__ a, int n){
  int i = blockIdx.x*256 + threadIdx.x; if (i<n) a[i]=0;
}
__global__ __launch_bounds__(256) void k_degi(const int* __restrict__ dst, int* __restrict__ cnt, int E){
  int e = blockIdx.x*256 + threadIdx.x; if (e<E) atomicAdd(&cnt[dst[e]], 1);
}
__global__ __launch_bounds__(256) void k_dinv(const int* __restrict__ cnt, float* __restrict__ dinv, int n){
  int i = blockIdx.x*256 + threadIdx.x; if (i<n) dinv[i] = rsqrtf((float)cnt[i] + 1.0f);
}
__global__ __launch_bounds__(256) void k_scan1(int* __restrict__ a, int* __restrict__ bsums, int n){
  __shared__ int sd[256];
  int tid = threadIdx.x;
  int base = blockIdx.x*1024 + tid*4;
  int v0 = (base+0<n)?a[base+0]:0;
  int v1 = (base+1<n)?a[base+1]:0;
  int v2 = (base+2<n)?a[base+2]:0;
  int v3 = (base+3<n)?a[base+3]:0;
  int ts = v0+v1+v2+v3;
  sd[tid]=ts; __syncthreads();
  for (int off=1; off<256; off<<=1){
    int t = (tid>=off)? sd[tid-off] : 0;
    __syncthreads();
    sd[tid]+=t;
    __syncthreads();
  }
  int excl = sd[tid]-ts;
  if (tid==255) bsums[blockIdx.x]=sd[255];
  if (base+0<n) a[base+0]=excl;
  if (base+1<n) a[base+1]=excl+v0;
  if (base+2<n) a[base+2]=excl+v0+v1;
  if (base+3<n) a[base+3]=excl+v0+v1+v2;
}
__global__ void k_scan2(int* __restrict__ bsums, int nb){
  if (threadIdx.x==0 && blockIdx.x==0){
    int run=0;
    for (int i=0;i<nb;i++){ int t=bsums[i]; bsums[i]=run; run+=t; }
  }
}
__global__ __launch_bounds__(256) void k_scan3(int* __restrict__ a, const int* __restrict__ bsums, int n){
  int i = blockIdx.x*256+threadIdx.x;
  if (i<n) a[i]+=bsums[i>>10];
}
__global__ __launch_bounds__(256) void k_reorder(const int* __restrict__ src, const int* __restrict__ dst,
    int* __restrict__ cursor, int* __restrict__ srcs, int E){
  int e = blockIdx.x*256 + threadIdx.x;
  if (e>=E) return;
  int pos = atomicAdd(&cursor[dst[e]], 1);
  srcs[pos] = src[e];
}

// ---------- gather aggregation: out[d] = dinv[d] * (tp[d] + sum_{s in N(d)} tp[s]) ----------
__global__ __launch_bounds__(256) void k_agg(const int* __restrict__ cend,
    const int* __restrict__ srcs, const float* __restrict__ dinv,
    const float* __restrict__ tp, float* __restrict__ out, int n)
{
  int node = blockIdx.x*4 + (threadIdx.x>>6);
  if (node >= n) return;
  const int lane = threadIdx.x & 63;
  const int c = lane<<1;
  int beg = (node==0) ? 0 : cend[node-1];
  int end = cend[node];
  float2 acc = *(const float2*)(tp + (size_t)node*128 + c);
  int e = beg;
  for (; e+4<=end; e+=4){
    int s0=srcs[e], s1=srcs[e+1], s2=srcs[e+2], s3=srcs[e+3];
    float2 v0 = *(const float2*)(tp + (size_t)s0*128 + c);
    float2 v1 = *(const float2*)(tp + (size_t)s1*128 + c);
    float2 v2 = *(const float2*)(tp + (size_t)s2*128 + c);
    float2 v3 = *(const float2*)(tp + (size_t)s3*128 + c);
    acc.x += (v0.x+v1.x) + (v2.x+v3.x);
    acc.y += (v0.y+v1.y) + (v2.y+v3.y);
  }
  for (; e<end; ++e){
    int s = srcs[e];
    float2 v = *(const float2*)(tp + (size_t)s*128 + c);
    acc.x += v.x; acc.y += v.y;
  }
  float di = dinv[node];
  float2 r; r.x = acc.x*di; r.y = acc.y*di;
  *(float2*)(out + (size_t)node*128 + c) = r;
}

extern "C" void kernel_launch(void* const* d_in, const int* in_sizes, int n_in,
                              void* d_out, int out_size, void* d_ws, size_t ws_size,
                              hipStream_t stream)
{
  const float* x   = (const float*)d_in[0];
  const int*   ei  = (const int*)d_in[1];
  const float *W1=(const float*)d_in[2],  *b1=(const float*)d_in[3];
  const float *W2=(const float*)d_in[4],  *b2=(const float*)d_in[5];
  const float *W3=(const float*)d_in[6],  *b3=(const float*)d_in[7];
  const float *W4=(const float*)d_in[8],  *b4=(const float*)d_in[9];
  const float *Wc1=(const float*)d_in[10],*bc1=(const float*)d_in[11];
  const float *Wc2=(const float*)d_in[12],*bc2=(const float*)d_in[13];
  const float *W5=(const float*)d_in[14], *b5=(const float*)d_in[15];
  float* out = (float*)d_out;

  const int n = in_sizes[0] / 5;
  const int E = in_sizes[1] / 2;
  const int* esrc = ei;
  const int* edst = ei + E;

  const int nb = (n + 1023)/1024;
  dim3 B256(256), B512(512);
  const int G256 = (n + 255)/256;   // BM=256 gemms
  const int G512 = (n + 511)/512;   // BM=512 gemm (W5)

  // workspace layout
  char* p = (char*)d_ws;
  float* hA   = (float*)p;            p += (size_t)n*128*4;
  float* hB   = (float*)p;            p += (size_t)n*128*4;
  float* dinv = (float*)p;            p += (size_t)n*4;
  int*   cursor = (int*)p;            p += (size_t)n*4;
  int*   bsums  = (int*)p;            p += (size_t)nb*4;
  int*   srcs   = (int*)p;            p += (size_t)E*4;

  // --- MLP head ---
  k_lin5<<<dim3((n*64 + 255)/256), B256, 0, stream>>>(x, W1, b1, hA, n);
  k_mgemm<64,128,128,0,2,4,2><<<dim3(G256), B512, 0, stream>>>(hA, W2, nullptr, b2, nullptr, hB, n);
  k_mgemm<128,128,128,0,3,4,2><<<dim3(G256), B512, 0, stream>>>(hB, W3, nullptr, b3, nullptr, hA, n);
  k_mgemm<128,128,128,0,3,4,2><<<dim3(G256), B512, 0, stream>>>(hA, W4, nullptr, b4, nullptr, hB, n);

  // --- CSR build ---
  k_zeroi<<<dim3((n+255)/256), B256, 0, stream>>>(cursor, n);
  k_degi<<<dim3((E+255)/256), B256, 0, stream>>>(edst, cursor, E);
  k_dinv<<<dim3((n+255)/256), B256, 0, stream>>>(cursor, dinv, n);
  k_scan1<<<dim3(nb), B256, 0, stream>>>(cursor, bsums, n);
  k_scan2<<<dim3(1), dim3(64), 0, stream>>>(bsums, nb);
  k_scan3<<<dim3((n+255)/256), B256, 0, stream>>>(cursor, bsums, n);
  k_reorder<<<dim3((E+255)/256), B256, 0, stream>>>(esrc, edst, cursor, srcs, E);
  // after k_reorder, cursor[d] = end of segment d

  // --- conv1: tp1 = (h4 @ Wc1.T)*dinv -> hA ; agg1 -> hB ---
  k_mgemm<128,128,128,0,4,4,2><<<dim3(G256), B512, 0, stream>>>(hB, Wc1, nullptr, nullptr, dinv, hA, n);
  k_agg<<<dim3((n+3)/4), B256, 0, stream>>>(cursor, srcs, dinv, hA, hB, n);

  // --- conv2: tp2 = (relu(agg1+bc1) @ Wc2.T)*dinv -> hA ; agg2 -> hB ---
  k_mgemm<128,128,128,1,4,4,2><<<dim3(G256), B512, 0, stream>>>(hB, Wc2, bc1, nullptr, dinv, hA, n);
  k_agg<<<dim3((n+3)/4), B256, 0, stream>>>(cursor, srcs, dinv, hA, hB, n);

  // --- final: out = relu(agg2+bc2) @ W5.T + b5 ---
  k_mgemm<128,64,60,1,1,8,1><<<dim3(G512), B512, 0, stream>>>(hB, W5, bc2, b5, nullptr, out, n);
}

// Round 4
// 475.778 us; speedup vs baseline: 13.8467x; 2.1510x over previous
//
#include <hip/hip_runtime.h>
#include <hip/hip_fp16.h>

typedef __attribute__((ext_vector_type(8))) short bf16x8;
typedef __attribute__((ext_vector_type(4))) float f32x4;

__device__ __forceinline__ float frelu(float v){ return fmaxf(v, 0.f); }
__device__ __forceinline__ short f2bf(float f){
  unsigned u = __float_as_uint(f);
  unsigned r = (u + 0x7fffu + ((u>>16)&1u)) >> 16;
  return (short)r;
}
__device__ __forceinline__ float bf2f(short h){
  return __uint_as_float(((unsigned)(unsigned short)h) << 16);
}

// ---------- k1: h1 = relu(x @ W1.T + b1), x[N][5], W1[64][5] ----------
__global__ __launch_bounds__(256) void k_lin5(const float* __restrict__ x,
    const float* __restrict__ W1, const float* __restrict__ b1,
    float* __restrict__ out, int n)
{
  int t = blockIdx.x*256 + threadIdx.x;
  int node = t >> 6, c = t & 63;
  if (node >= n) return;
  float acc = b1[c];
  const float* xr = x + (size_t)node*5;
  const float* wr = W1 + c*5;
  #pragma unroll
  for (int k=0;k<5;k++) acc = fmaf(xr[k], wr[k], acc);
  out[(size_t)node*64 + c] = frelu(acc);
}

// ---------- MFMA split-bf16 GEMM: Out = EPI( PRE(A) @ W.T ) ----------
// PRE: 0 id, 1 relu(a + bpre[k])
// EPI: 1 +bpost, 2 relu(+bpost), 3 relu(+bpost)+A[node][col] (K==BN),
//      4 *dscale[node] (fp32 out), 5 *dscale[node] -> fp16 out
template<int K, int BN, int COLS_REAL, int PRE, int EPI, int WRG, int WCG>
__global__ __launch_bounds__(512) void k_mgemm(const float* __restrict__ A,
    const float* __restrict__ W, const float* __restrict__ bpre,
    const float* __restrict__ bpost, const float* __restrict__ dscale,
    float* __restrict__ Out, int n)
{
  constexpr int BM = WRG*64;
  __shared__ __align__(16) short sAh[BM*32];
  __shared__ __align__(16) short sAl[BM*32];
  __shared__ __align__(16) short sWh[BN*32];
  __shared__ __align__(16) short sWl[BN*32];

  const int tid = threadIdx.x;
  const int nb0 = blockIdx.x * BM;
  const int l = tid & 63;
  const int w = tid >> 6;
  const int wr = w % WRG;
  const int wc = w / WRG;
  const int lrow = l & 15;
  const int koct = l >> 4;

  f32x4 acc[4][4];
  #pragma unroll
  for (int i=0;i<4;i++)
    #pragma unroll
    for (int j=0;j<4;j++) acc[i][j] = (f32x4){0.f,0.f,0.f,0.f};

  for (int kc = 0; kc < K/32; ++kc) {
    if (kc) __syncthreads();
    #pragma unroll
    for (int t = 0; t < BM/128; ++t) {
      int idx = tid + t*512;
      int row = idx >> 2, kq = idx & 3;
      int node = nb0 + row;
      float a[8];
      if (node < n) {
        const float* g = A + (size_t)node*K + kc*32 + kq*8;
        float4 v0 = *(const float4*)g;
        float4 v1 = *(const float4*)(g+4);
        a[0]=v0.x; a[1]=v0.y; a[2]=v0.z; a[3]=v0.w;
        a[4]=v1.x; a[5]=v1.y; a[6]=v1.z; a[7]=v1.w;
      } else {
        #pragma unroll
        for (int j=0;j<8;j++) a[j]=0.f;
      }
      if constexpr (PRE == 1) {
        const float* bp = bpre + kc*32 + kq*8;
        float4 b0 = *(const float4*)bp;
        float4 b1 = *(const float4*)(bp+4);
        a[0]=frelu(a[0]+b0.x); a[1]=frelu(a[1]+b0.y);
        a[2]=frelu(a[2]+b0.z); a[3]=frelu(a[3]+b0.w);
        a[4]=frelu(a[4]+b1.x); a[5]=frelu(a[5]+b1.y);
        a[6]=frelu(a[6]+b1.z); a[7]=frelu(a[7]+b1.w);
      }
      union { short s[8]; bf16x8 v; } ph, pl;
      #pragma unroll
      for (int j=0;j<8;j++) {
        short h = f2bf(a[j]);
        ph.s[j] = h;
        pl.s[j] = f2bf(a[j] - bf2f(h));
      }
      int byte = (row<<6) | (kq<<4);
      byte ^= (row&7)<<4;
      *(bf16x8*)((char*)sAh + byte) = ph.v;
      *(bf16x8*)((char*)sAl + byte) = pl.v;
    }
    if (BN*4 >= 512 || tid < BN*4) {
      int idx = tid;
      int c = idx >> 2, kq = idx & 3;
      float a[8];
      if (COLS_REAL == BN || c < COLS_REAL) {
        const float* g = W + (size_t)c*K + kc*32 + kq*8;
        float4 v0 = *(const float4*)g;
        float4 v1 = *(const float4*)(g+4);
        a[0]=v0.x; a[1]=v0.y; a[2]=v0.z; a[3]=v0.w;
        a[4]=v1.x; a[5]=v1.y; a[6]=v1.z; a[7]=v1.w;
      } else {
        #pragma unroll
        for (int j=0;j<8;j++) a[j]=0.f;
      }
      union { short s[8]; bf16x8 v; } ph, pl;
      #pragma unroll
      for (int j=0;j<8;j++) {
        short h = f2bf(a[j]);
        ph.s[j] = h;
        pl.s[j] = f2bf(a[j] - bf2f(h));
      }
      int byte = (c<<6) | (kq<<4);
      byte ^= (c&7)<<4;
      *(bf16x8*)((char*)sWh + byte) = ph.v;
      *(bf16x8*)((char*)sWl + byte) = pl.v;
    }
    __syncthreads();
    bf16x8 fah[4], fal[4], fwh[4], fwl[4];
    #pragma unroll
    for (int rf=0; rf<4; ++rf) {
      int row = wr*64 + rf*16 + lrow;
      int byte = (row<<6) | (koct<<4);
      byte ^= (row&7)<<4;
      fah[rf] = *(const bf16x8*)((const char*)sAh + byte);
      fal[rf] = *(const bf16x8*)((const char*)sAl + byte);
    }
    #pragma unroll
    for (int cf=0; cf<4; ++cf) {
      int c = wc*64 + cf*16 + lrow;
      int byte = (c<<6) | (koct<<4);
      byte ^= (c&7)<<4;
      fwh[cf] = *(const bf16x8*)((const char*)sWh + byte);
      fwl[cf] = *(const bf16x8*)((const char*)sWl + byte);
    }
    #pragma unroll
    for (int rf=0; rf<4; ++rf)
      #pragma unroll
      for (int cf=0; cf<4; ++cf) {
        acc[rf][cf] = __builtin_amdgcn_mfma_f32_16x16x32_bf16(fah[rf], fwh[cf], acc[rf][cf], 0,0,0);
        acc[rf][cf] = __builtin_amdgcn_mfma_f32_16x16x32_bf16(fah[rf], fwl[cf], acc[rf][cf], 0,0,0);
        acc[rf][cf] = __builtin_amdgcn_mfma_f32_16x16x32_bf16(fal[rf], fwh[cf], acc[rf][cf], 0,0,0);
      }
  }
  const int crow = (l >> 4) * 4;
  float bpc[4];
  if constexpr (EPI==1 || EPI==2 || EPI==3) {
    #pragma unroll
    for (int cf=0; cf<4; ++cf) {
      int col = wc*64 + cf*16 + (l & 15);
      bpc[cf] = (COLS_REAL == BN || col < COLS_REAL) ? bpost[col] : 0.f;
    }
  }
  #pragma unroll
  for (int rf=0; rf<4; ++rf) {
    #pragma unroll
    for (int reg=0; reg<4; ++reg) {
      int row = wr*64 + rf*16 + crow + reg;
      int node = nb0 + row;
      if (node >= n) continue;
      float ds = 1.f;
      if constexpr (EPI==4 || EPI==5) ds = dscale[node];
      #pragma unroll
      for (int cf=0; cf<4; ++cf) {
        int col = wc*64 + cf*16 + (l & 15);
        if (COLS_REAL != BN && col >= COLS_REAL) continue;
        float v = acc[rf][cf][reg];
        if constexpr (EPI==1) v += bpc[cf];
        if constexpr (EPI==2) v = frelu(v + bpc[cf]);
        if constexpr (EPI==3) v = frelu(v + bpc[cf]) + A[(size_t)node*K + col];
        if constexpr (EPI==4) v *= ds;
        if constexpr (EPI==5) {
          v *= ds;
          ((__half*)Out)[(size_t)node*COLS_REAL + col] = __float2half_rn(v);
        } else {
          Out[(size_t)node*COLS_REAL + col] = v;
        }
      }
    }
  }
}

// ---------- bucket sort of edges by dst (256 nodes / bucket) ----------
__global__ __launch_bounds__(512) void k_zero512(int* __restrict__ a, int m){
  int i = threadIdx.x; if (i<m) a[i]=0;
}
__global__ __launch_bounds__(512) void k_bhist(const int* __restrict__ dst,
    int* __restrict__ bcnt, int E, int nbuck){
  __shared__ int l[512];
  int tid = threadIdx.x;
  if (tid < nbuck) l[tid]=0;
  __syncthreads();
  for (int e = blockIdx.x*512 + tid; e < E; e += gridDim.x*512)
    atomicAdd(&l[((unsigned)dst[e])>>8], 1);
  __syncthreads();
  if (tid < nbuck && l[tid]) atomicAdd(&bcnt[tid], l[tid]);
}
__global__ __launch_bounds__(512) void k_bscan(const int* __restrict__ bcnt,
    int* __restrict__ bbase, int* __restrict__ bcur, int nbuck){
  __shared__ int sc[512];
  int tid = threadIdx.x;
  int v = (tid<nbuck) ? bcnt[tid] : 0;
  sc[tid]=v; __syncthreads();
  for (int off=1; off<512; off<<=1){
    int t = (tid>=off)? sc[tid-off] : 0;
    __syncthreads();
    sc[tid]+=t;
    __syncthreads();
  }
  if (tid<nbuck){ bbase[tid]=sc[tid]-v; bcur[tid]=sc[tid]-v; }
  if (tid==nbuck-1) bbase[nbuck]=sc[tid];
}
// coarse scatter: pack (src<<8)|(dst&255), block-reserved bucket ranges
__global__ __launch_bounds__(512) void k_bscatter(const int* __restrict__ src,
    const int* __restrict__ dst, int* __restrict__ bcur,
    unsigned* __restrict__ sorted, int E, int nbuck)
{
  __shared__ int lcnt[512];
  __shared__ int lbase[512];
  int tid = threadIdx.x;
  if (tid < nbuck) lcnt[tid]=0;
  __syncthreads();
  int e0 = blockIdx.x*8192;
  int e1 = min(e0+8192, E);
  for (int e = e0+tid; e < e1; e += 512)
    atomicAdd(&lcnt[((unsigned)dst[e])>>8], 1);
  __syncthreads();
  if (tid < nbuck) lbase[tid] = lcnt[tid] ? atomicAdd(&bcur[tid], lcnt[tid]) : 0;
  __syncthreads();
  if (tid < nbuck) lcnt[tid]=0;
  __syncthreads();
  for (int e = e0+tid; e < e1; e += 512){
    int d = dst[e];
    int k = ((unsigned)d)>>8;
    int pos = lbase[k] + atomicAdd(&lcnt[k], 1);
    sorted[pos] = (((unsigned)src[e])<<8) | ((unsigned)d & 255u);
  }
}
// fine sort within bucket (LDS), emit srcs in place + cend + dinv
__global__ __launch_bounds__(512) void k_finesort(unsigned* __restrict__ sorted,
    const int* __restrict__ bbase, int* __restrict__ cend,
    float* __restrict__ dinv, int n, int* __restrict__ fb)
{
  constexpr int CAP = 16384;
  __shared__ int lsorted[CAP];
  __shared__ int cnt[256], cur[256], sc[256];
  const int k = blockIdx.x;
  const int base = bbase[k], endb = bbase[k+1];
  const int m = endb - base;
  const int node0 = k<<8;
  const int tid = threadIdx.x;
  if (tid<256) cnt[tid]=0;
  __syncthreads();
  for (int i=tid; i<m; i+=512) atomicAdd(&cnt[sorted[base+i]&255u], 1);
  __syncthreads();
  int v=0;
  if (tid<256){ v=cnt[tid]; sc[tid]=v; }
  __syncthreads();
  for (int off=1; off<256; off<<=1){
    int t=0;
    if (tid>=off && tid<256) t=sc[tid-off];
    __syncthreads();
    if (tid<256) sc[tid]+=t;
    __syncthreads();
  }
  if (tid<256){
    cur[tid]=sc[tid]-v;
    int node = node0 + tid;
    if (node < n){
      cend[node] = base + sc[tid];
      dinv[node] = rsqrtf((float)v + 1.0f);
    }
  }
  __syncthreads();
  if (m <= CAP){
    for (int i=tid; i<m; i+=512){
      unsigned p = sorted[base+i];
      int pos = atomicAdd(&cur[p&255u], 1);
      lsorted[pos] = (int)(p>>8);
    }
    __syncthreads();
    for (int i=tid; i<m; i+=512) sorted[base+i] = (unsigned)lsorted[i];
  } else {
    // defensive fallback (never triggers for uniform-random dst): stage via global scratch
    for (int i=tid; i<m; i+=512) fb[base+i] = (int)sorted[base+i];
    __syncthreads();
    for (int i=tid; i<m; i+=512){
      unsigned p = (unsigned)fb[base+i];
      int pos = atomicAdd(&cur[p&255u], 1);
      sorted[base+pos] = p>>8;
    }
  }
}

// ---------- gather aggregation: out[d] = dinv[d] * (tp[d] + sum_{s in N(d)} tp[s]) ----------
__global__ __launch_bounds__(256) void k_agg(const int* __restrict__ cend,
    const unsigned* __restrict__ srcs, const float* __restrict__ dinv,
    const __half* __restrict__ tp, float* __restrict__ out, int n)
{
  int node = blockIdx.x*4 + (threadIdx.x>>6);
  if (node >= n) return;
  const int lane = threadIdx.x & 63;
  const __half2* tpp = (const __half2*)tp;   // row stride 64 half2
  int beg = (node==0) ? 0 : cend[node-1];
  int end = cend[node];
  float2 acc;
  { __half2 h = tpp[(size_t)node*64 + lane]; acc.x = __low2float(h); acc.y = __high2float(h); }
  int e = beg;
  for (; e+4<=end; e+=4){
    unsigned s0=srcs[e], s1=srcs[e+1], s2=srcs[e+2], s3=srcs[e+3];
    __half2 h0 = tpp[(size_t)s0*64 + lane];
    __half2 h1 = tpp[(size_t)s1*64 + lane];
    __half2 h2 = tpp[(size_t)s2*64 + lane];
    __half2 h3 = tpp[(size_t)s3*64 + lane];
    acc.x += (__low2float(h0)+__low2float(h1)) + (__low2float(h2)+__low2float(h3));
    acc.y += (__high2float(h0)+__high2float(h1)) + (__high2float(h2)+__high2float(h3));
  }
  for (; e<end; ++e){
    __half2 h = tpp[(size_t)srcs[e]*64 + lane];
    acc.x += __low2float(h); acc.y += __high2float(h);
  }
  float di = dinv[node];
  float2 r; r.x = acc.x*di; r.y = acc.y*di;
  *(float2*)(out + (size_t)node*128 + (lane<<1)) = r;
}

extern "C" void kernel_launch(void* const* d_in, const int* in_sizes, int n_in,
                              void* d_out, int out_size, void* d_ws, size_t ws_size,
                              hipStream_t stream)
{
  const float* x   = (const float*)d_in[0];
  const int*   ei  = (const int*)d_in[1];
  const float *W1=(const float*)d_in[2],  *b1=(const float*)d_in[3];
  const float *W2=(const float*)d_in[4],  *b2=(const float*)d_in[5];
  const float *W3=(const float*)d_in[6],  *b3=(const float*)d_in[7];
  const float *W4=(const float*)d_in[8],  *b4=(const float*)d_in[9];
  const float *Wc1=(const float*)d_in[10],*bc1=(const float*)d_in[11];
  const float *Wc2=(const float*)d_in[12],*bc2=(const float*)d_in[13];
  const float *W5=(const float*)d_in[14], *b5=(const float*)d_in[15];
  float* out = (float*)d_out;

  const int n = in_sizes[0] / 5;
  const int E = in_sizes[1] / 2;
  const int* esrc = ei;
  const int* edst = ei + E;
  const int nbuck = (n + 255) >> 8;

  dim3 B256(256), B512(512);
  const int G256 = (n + 255)/256;
  const int G512 = (n + 511)/512;

  // workspace layout (~116 MB)
  char* p = (char*)d_ws;
  float* hA    = (float*)p;           p += (size_t)n*128*4;
  float* hB    = (float*)p;           p += (size_t)n*128*4;
  float* dinv  = (float*)p;           p += (size_t)n*4;
  int*   cend  = (int*)p;             p += (size_t)n*4;
  unsigned* sortedp = (unsigned*)p;   p += (size_t)E*4;
  int*   bcnt  = (int*)p;             p += 512*4;
  int*   bbase = (int*)p;             p += 513*4;
  int*   bcur  = (int*)p;             p += 512*4;

  // --- MLP head ---
  k_lin5<<<dim3((n*64 + 255)/256), B256, 0, stream>>>(x, W1, b1, hA, n);
  k_mgemm<64,128,128,0,2,4,2><<<dim3(G256), B512, 0, stream>>>(hA, W2, nullptr, b2, nullptr, hB, n);
  k_mgemm<128,128,128,0,3,4,2><<<dim3(G256), B512, 0, stream>>>(hB, W3, nullptr, b3, nullptr, hA, n);
  k_mgemm<128,128,128,0,3,4,2><<<dim3(G256), B512, 0, stream>>>(hA, W4, nullptr, b4, nullptr, hB, n);

  // --- bucket-sorted CSR build (hA is dead here; used only as impossible-case scratch) ---
  k_zero512<<<dim3(1), B512, 0, stream>>>(bcnt, nbuck);
  k_bhist<<<dim3(512), B512, 0, stream>>>(edst, bcnt, E, nbuck);
  k_bscan<<<dim3(1), B512, 0, stream>>>(bcnt, bbase, bcur, nbuck);
  k_bscatter<<<dim3((E + 8191)/8192), B512, 0, stream>>>(esrc, edst, bcur, sortedp, E, nbuck);
  k_finesort<<<dim3(nbuck), B512, 0, stream>>>(sortedp, bbase, cend, dinv, n, (int*)hA);

  // --- conv1: tp1(half) = (h4 @ Wc1.T)*dinv -> hA ; agg1 -> hB ---
  k_mgemm<128,128,128,0,5,4,2><<<dim3(G256), B512, 0, stream>>>(hB, Wc1, nullptr, nullptr, dinv, hA, n);
  k_agg<<<dim3((n+3)/4), B256, 0, stream>>>(cend, sortedp, dinv, (const __half*)hA, hB, n);

  // --- conv2: tp2(half) = (relu(agg1+bc1) @ Wc2.T)*dinv -> hA ; agg2 -> hB ---
  k_mgemm<128,128,128,1,5,4,2><<<dim3(G256), B512, 0, stream>>>(hB, Wc2, bc1, nullptr, dinv, hA, n);
  k_agg<<<dim3((n+3)/4), B256, 0, stream>>>(cend, sortedp, dinv, (const __half*)hA, hB, n);

  // --- final: out = relu(agg2+bc2) @ W5.T + b5 ---
  k_mgemm<128,64,60,1,1,8,1><<<dim3(G512), B512, 0, stream>>>(hB, W5, bc2, b5, nullptr, out, n);
}